// Round 5
// baseline (1474.735 us; speedup 1.0000x reference)
//
#include <hip/hip_runtime.h>
#include <hip/hip_bf16.h>
#include <math.h>

// ---------------------------------------------------------------------------
// GCN-VAE encoder, round 7: fuse agg+GEMM per layer.
// r6 post-mortem: barrier-free GEMM gained only 12us -- the remaining waste
// is the agg->g->GEMM global round-trip (g writes 128MB + A re-reads ~460MB
// across layers) and 8 full-chip launch ramps.
// New structure (k_fused_relu<K,NCG> / k_fused_dual):
//   - block owns 128 nodes x full Nc (NB=1, gather done once per node)
//   - phase 1: gather g rows straight into LDS (same slot order, same f2bf
//     rounding as k_agg -> bit-identical)
//   - phase 2: per-wave col-group loop; a-frags from LDS, b-frags streamed
//     from GLOBAL (weights <=131KB, L2-resident, shared by all blocks).
//     Same MFMA order -> bit-identical outputs.
// LDS 18/35/51/68KB -> 4/4/3/2 blocks/CU; gather of one block overlaps GEMM
// of another. k_agg and the standalone MFMA GEMMs are gone.
// ---------------------------------------------------------------------------

#define THREADS 256

typedef short s8v __attribute__((ext_vector_type(8)));   // 8 bf16 = 4 VGPR
typedef float f4v __attribute__((ext_vector_type(4)));   // MFMA accum

__device__ inline float bf_lo(unsigned int u) {
    union { unsigned int i; float f; } c; c.i = u << 16; return c.f;
}
__device__ inline float bf_hi(unsigned int u) {
    union { unsigned int i; float f; } c; c.i = u & 0xffff0000u; return c.f;
}
__device__ inline unsigned short f2bf(float f) {
    __hip_bfloat16 h = __float2bfloat16(f);
    return *reinterpret_cast<unsigned short*>(&h);
}
__device__ inline float bf2f(unsigned short u) {
    union { unsigned int i; float f; } c; c.i = ((unsigned int)u) << 16; return c.f;
}

// ------------------------- graph structure ---------------------------------

__global__ void k_count(const int* __restrict__ col, int* __restrict__ counts, int E) {
    int e = blockIdx.x * blockDim.x + threadIdx.x;
    if (e < E) atomicAdd(&counts[col[e]], 1);
}

__global__ void k_dinv(const int* __restrict__ counts, float* __restrict__ dinv, int N) {
    int i = blockIdx.x * blockDim.x + threadIdx.x;
    if (i < N) dinv[i] = rsqrtf((float)(counts[i] + 1));   // +1 self loop
}

__global__ __launch_bounds__(1024) void k_scan(const int* __restrict__ counts,
                                               int* __restrict__ offsets, int N) {
    __shared__ int ssum[1024];
    int tid = threadIdx.x;
    int chunk = (N + 1023) / 1024;
    int begin = tid * chunk;
    int end = begin + chunk; if (end > N) end = N;
    int s = 0;
    for (int i = begin; i < end; ++i) s += counts[i] + 1;
    ssum[tid] = s;
    __syncthreads();
    for (int off = 1; off < 1024; off <<= 1) {
        int v = 0;
        if (tid >= off) v = ssum[tid - off];
        __syncthreads();
        if (tid >= off) ssum[tid] += v;
        __syncthreads();
    }
    int prefix = (tid == 0) ? 0 : ssum[tid - 1];
    for (int i = begin; i < end; ++i) {
        offsets[i] = prefix;
        prefix += counts[i] + 1;
    }
    if (end == N && begin < N) offsets[N] = prefix;
}

__global__ void k_init_cursor(const int* __restrict__ offsets, int* __restrict__ cursor, int N) {
    int i = blockIdx.x * blockDim.x + threadIdx.x;
    if (i < N) cursor[i] = offsets[i];
}

__global__ void k_scatter(const int* __restrict__ row, const int* __restrict__ col,
                          const float* __restrict__ dinv, int* __restrict__ cursor,
                          int* __restrict__ csr_row, float* __restrict__ csr_norm,
                          int E, int N) {
    int e = blockIdx.x * blockDim.x + threadIdx.x;
    if (e < E) {
        int r = row[e], c = col[e];
        int slot = atomicAdd(&cursor[c], 1);
        csr_row[slot] = r;
        csr_norm[slot] = dinv[r] * dinv[c];
    } else if (e < E + N) {
        int i = e - E;
        int slot = atomicAdd(&cursor[i], 1);
        csr_row[slot] = i;
        float d = dinv[i];
        csr_norm[slot] = d * d;
    }
}

// ------------------------- casts / weight prep -----------------------------

__global__ void k_cast_bf16(const float* __restrict__ src, unsigned short* __restrict__ dst, int n) {
    int i = blockIdx.x * blockDim.x + threadIdx.x;
    if (i < n) dst[i] = f2bf(src[i]);
}

// W [K,Nc] fp32 -> WT [Nc,K] bf16
__global__ void k_prep_w(const float* __restrict__ W, unsigned short* __restrict__ WT,
                         int K, int Nc) {
    int id = blockIdx.x * blockDim.x + threadIdx.x;
    if (id < K * Nc) {
        int k = id / Nc, n = id % Nc;
        WT[(size_t)n * K + k] = f2bf(W[id]);
    }
}

// ------------------------- fused agg + MFMA GEMM (relu layers) -------------
// out[node, :] = relu( (Sum_slots nrm * h[src, :]) @ W + b ), bf16 out.
// Block: 128 nodes x full Nc. Gather -> LDS, one barrier, GEMM.
// a-frags from LDS; b-frags from global (L2-resident weights).
template<int K, int NCG>
__global__ __launch_bounds__(512) void k_fused_relu(
    const unsigned short* __restrict__ h,      // [N,K] bf16
    const int* __restrict__ offsets,
    const int* __restrict__ csr_row,
    const float* __restrict__ csr_nrm,
    const unsigned short* __restrict__ WT,     // [NCG*64, K] bf16
    const float* __restrict__ bias,
    unsigned short* __restrict__ out,          // [N, NCG*64] bf16
    int N) {
    constexpr int LDB = K + 8;                 // 2-way LDS alias max
    constexpr int CH = K / 8;                  // uint4 chunks per row
    constexpr int Nc = NCG * 64;
    __shared__ unsigned short sG[128 * LDB];
    const int tid = threadIdx.x;
    const int bm = blockIdx.x * 128;

    // ---- phase 1: gather into LDS ----
    for (int task = tid; task < 128 * CH; task += 512) {
        const int ln = task / CH;
        const int c8 = (task - ln * CH) * 8;
        const int node = bm + ln;
        uint4 o = make_uint4(0u, 0u, 0u, 0u);
        if (node < N) {
            float a0=0.f,a1=0.f,a2=0.f,a3=0.f,a4=0.f,a5=0.f,a6=0.f,a7=0.f;
            const int off0 = offsets[node], off1 = offsets[node + 1];
            for (int sl = off0; sl < off1; ++sl) {
                int r = csr_row[sl];
                float w = csr_nrm[sl];
                uint4 v = *(const uint4*)(h + (size_t)r * K + c8);
                a0 += w * bf_lo(v.x); a1 += w * bf_hi(v.x);
                a2 += w * bf_lo(v.y); a3 += w * bf_hi(v.y);
                a4 += w * bf_lo(v.z); a5 += w * bf_hi(v.z);
                a6 += w * bf_lo(v.w); a7 += w * bf_hi(v.w);
            }
            o.x = (unsigned)f2bf(a0) | ((unsigned)f2bf(a1) << 16);
            o.y = (unsigned)f2bf(a2) | ((unsigned)f2bf(a3) << 16);
            o.z = (unsigned)f2bf(a4) | ((unsigned)f2bf(a5) << 16);
            o.w = (unsigned)f2bf(a6) | ((unsigned)f2bf(a7) << 16);
        }
        *(uint4*)(&sG[ln * LDB + c8]) = o;
    }
    __syncthreads();

    // ---- phase 2: GEMM ----
    const int wave = tid >> 6;                 // owns rows [wave*16, +16)
    const int lane = tid & 63;
    const int fr = lane & 15;
    const int fk = (lane >> 4) * 8;
    const int col_l = lane & 15;
    const int row_q = (lane >> 4) * 4;

    for (int cg = 0; cg < NCG; ++cg) {
        f4v acc[4];
        #pragma unroll
        for (int j = 0; j < 4; ++j) acc[j] = (f4v){0.f, 0.f, 0.f, 0.f};
        #pragma unroll
        for (int k0 = 0; k0 < K; k0 += 32) {
            const int kk = k0 + fk;
            s8v a0 = *(const s8v*)(&sG[(wave * 16 + fr) * LDB + kk]);
            #pragma unroll
            for (int nt = 0; nt < 4; ++nt) {
                s8v b = *(const s8v*)(WT + (size_t)(cg * 64 + nt * 16 + fr) * K + kk);
                acc[nt] = __builtin_amdgcn_mfma_f32_16x16x32_bf16(a0, b, acc[nt], 0, 0, 0);
            }
        }
        #pragma unroll
        for (int nt = 0; nt < 4; ++nt) {
            const int col = cg * 64 + nt * 16 + col_l;
            const float bb = bias[col];
            #pragma unroll
            for (int i = 0; i < 4; ++i) {
                int row = bm + wave * 16 + row_q + i;
                if (row < N)
                    out[(size_t)row * Nc + col] = f2bf(fmaxf(acc[nt][i] + bb, 0.f));
            }
        }
    }
}

// ------------------------- fused agg + dual GEMM + reparam -----------------
// g4 = agg(h3) in LDS; mu = g4@Wm+bmu; lv = g4@Wl+blv;
// amvo = mu + eps*exp(0.5*lv). K=256, Nc=256 fixed. fp32 out.
__global__ __launch_bounds__(512) void k_fused_dual(
    const unsigned short* __restrict__ h,      // [N,256] bf16
    const int* __restrict__ offsets,
    const int* __restrict__ csr_row,
    const float* __restrict__ csr_nrm,
    const unsigned short* __restrict__ WTm,
    const unsigned short* __restrict__ WTl,
    const float* __restrict__ bmu,
    const float* __restrict__ blv,
    const float* __restrict__ eps,
    float* __restrict__ mu,
    float* __restrict__ lv,
    float* __restrict__ amvo,
    int N) {
    constexpr int K = 256;
    constexpr int LDB = K + 8;
    constexpr int CH = K / 8;
    constexpr int Nc = 256;
    __shared__ unsigned short sG[128 * LDB];   // 67.6 KB
    const int tid = threadIdx.x;
    const int bm = blockIdx.x * 128;

    for (int task = tid; task < 128 * CH; task += 512) {
        const int ln = task / CH;
        const int c8 = (task - ln * CH) * 8;
        const int node = bm + ln;
        uint4 o = make_uint4(0u, 0u, 0u, 0u);
        if (node < N) {
            float a0=0.f,a1=0.f,a2=0.f,a3=0.f,a4=0.f,a5=0.f,a6=0.f,a7=0.f;
            const int off0 = offsets[node], off1 = offsets[node + 1];
            for (int sl = off0; sl < off1; ++sl) {
                int r = csr_row[sl];
                float w = csr_nrm[sl];
                uint4 v = *(const uint4*)(h + (size_t)r * K + c8);
                a0 += w * bf_lo(v.x); a1 += w * bf_hi(v.x);
                a2 += w * bf_lo(v.y); a3 += w * bf_hi(v.y);
                a4 += w * bf_lo(v.z); a5 += w * bf_hi(v.z);
                a6 += w * bf_lo(v.w); a7 += w * bf_hi(v.w);
            }
            o.x = (unsigned)f2bf(a0) | ((unsigned)f2bf(a1) << 16);
            o.y = (unsigned)f2bf(a2) | ((unsigned)f2bf(a3) << 16);
            o.z = (unsigned)f2bf(a4) | ((unsigned)f2bf(a5) << 16);
            o.w = (unsigned)f2bf(a6) | ((unsigned)f2bf(a7) << 16);
        }
        *(uint4*)(&sG[ln * LDB + c8]) = o;
    }
    __syncthreads();

    const int wave = tid >> 6;
    const int lane = tid & 63;
    const int fr = lane & 15;
    const int fk = (lane >> 4) * 8;
    const int col_l = lane & 15;
    const int row_q = (lane >> 4) * 4;

    for (int cg = 0; cg < 4; ++cg) {
        f4v accM[4], accL[4];
        #pragma unroll
        for (int j = 0; j < 4; ++j) {
            accM[j] = (f4v){0.f, 0.f, 0.f, 0.f};
            accL[j] = (f4v){0.f, 0.f, 0.f, 0.f};
        }
        #pragma unroll
        for (int k0 = 0; k0 < K; k0 += 32) {
            const int kk = k0 + fk;
            s8v a0 = *(const s8v*)(&sG[(wave * 16 + fr) * LDB + kk]);
            #pragma unroll
            for (int nt = 0; nt < 4; ++nt) {
                const size_t woff = (size_t)(cg * 64 + nt * 16 + fr) * K + kk;
                s8v bm_ = *(const s8v*)(WTm + woff);
                s8v bl_ = *(const s8v*)(WTl + woff);
                accM[nt] = __builtin_amdgcn_mfma_f32_16x16x32_bf16(a0, bm_, accM[nt], 0, 0, 0);
                accL[nt] = __builtin_amdgcn_mfma_f32_16x16x32_bf16(a0, bl_, accL[nt], 0, 0, 0);
            }
        }
        #pragma unroll
        for (int nt = 0; nt < 4; ++nt) {
            const int col = cg * 64 + nt * 16 + col_l;
            const float bM = bmu[col];
            const float bL = blv[col];
            #pragma unroll
            for (int i = 0; i < 4; ++i) {
                int row = bm + wave * 16 + row_q + i;
                if (row < N) {
                    size_t idx = (size_t)row * Nc + col;
                    float vm = accM[nt][i] + bM;
                    float vl = accL[nt][i] + bL;
                    mu[idx] = vm;
                    lv[idx] = vl;
                    amvo[idx] = vm + eps[idx] * expf(0.5f * vl);
                }
            }
        }
    }
}

// ------------------------- FC layers (fp32, latency-optimized) -------------
__global__ __launch_bounds__(256) void k_fc1(const float* __restrict__ x2,
                                             const float* __restrict__ W,
                                             const float* __restrict__ bias,
                                             float* __restrict__ hid,
                                             int K, int Nc) {
    const int m = blockIdx.x;
    const int t = threadIdx.x;
    __shared__ float sx[256];
    for (int k = t; k < K; k += 256) sx[k] = x2[(size_t)m * K + k];
    __syncthreads();
    const int nc4 = Nc >> 2;
    const float4* Wv = (const float4*)W;
    float4 acc = make_float4(0.f, 0.f, 0.f, 0.f);
    #pragma unroll 4
    for (int k = 0; k < K; ++k) {
        float a = sx[k];
        float4 w = Wv[(size_t)k * nc4 + t];
        acc.x += a * w.x; acc.y += a * w.y;
        acc.z += a * w.z; acc.w += a * w.w;
    }
    float4 b = ((const float4*)bias)[t];
    float4 r;
    r.x = fmaxf(acc.x + b.x, 0.f);
    r.y = fmaxf(acc.y + b.y, 0.f);
    r.z = fmaxf(acc.z + b.z, 0.f);
    r.w = fmaxf(acc.w + b.w, 0.f);
    ((float4*)hid)[(size_t)m * nc4 + t] = r;
}

__global__ __launch_bounds__(128) void k_fc2(const float* __restrict__ hid,
                                             const float* __restrict__ W,
                                             const float* __restrict__ bias,
                                             float* __restrict__ out,
                                             int K, int Nc) {
    const int m = blockIdx.x;
    const int c = threadIdx.x;
    __shared__ float sh[1024];
    for (int k = c; k < K; k += 128) sh[k] = hid[(size_t)m * K + k];
    __syncthreads();
    float a0 = 0.f, a1 = 0.f, a2 = 0.f, a3 = 0.f;
    for (int k = 0; k < K; k += 4) {
        a0 += sh[k    ] * W[(size_t)(k    ) * Nc + c];
        a1 += sh[k + 1] * W[(size_t)(k + 1) * Nc + c];
        a2 += sh[k + 2] * W[(size_t)(k + 2) * Nc + c];
        a3 += sh[k + 3] * W[(size_t)(k + 3) * Nc + c];
    }
    out[(size_t)m * Nc + c] = (a0 + a1) + (a2 + a3) + bias[c];
}

// ------------------------- misc --------------------------------------------

__global__ void k_gstart(const int* __restrict__ batch, int* __restrict__ gstart, int Nn, int B) {
    int b = blockIdx.x * blockDim.x + threadIdx.x;
    if (b > B) return;
    int lo = 0, hi = Nn;
    while (lo < hi) {
        int mid = (lo + hi) >> 1;
        if (batch[mid] < b) lo = mid + 1; else hi = mid;
    }
    gstart[b] = lo;
}

// max-pool over bf16 h3 -> fp32 x2.
// grid (B, F/64), block (64, 4): 4-way row parallelism + LDS tree reduce.
__global__ void k_pool_max(const unsigned short* __restrict__ h, const int* __restrict__ gstart,
                           float* __restrict__ x2, int F) {
    int b = blockIdx.x;
    int c = blockIdx.y * 64 + threadIdx.x;
    int s = gstart[b], e = gstart[b + 1];
    float mv = -INFINITY;
    for (int i = s + threadIdx.y; i < e; i += 4)
        mv = fmaxf(mv, bf2f(h[(size_t)i * F + c]));
    __shared__ float red[4][64];
    red[threadIdx.y][threadIdx.x] = mv;
    __syncthreads();
    if (threadIdx.y == 0) {
        mv = fmaxf(fmaxf(red[0][threadIdx.x], red[1][threadIdx.x]),
                   fmaxf(red[2][threadIdx.x], red[3][threadIdx.x]));
        x2[(size_t)b * F + c] = mv;
    }
}

static inline int ceil_div(int a, int b) { return (a + b - 1) / b; }

extern "C" void kernel_launch(void* const* d_in, const int* in_sizes, int n_in,
                              void* d_out, int out_size, void* d_ws, size_t ws_size,
                              hipStream_t stream) {
    const int F0 = 64;
    const int N = in_sizes[0] / F0;            // 100000
    const int E = in_sizes[1] / 2;             // 400000
    const int F4 = 4 * F0;                     // 256
    const int B = (out_size - 3 * N * F4) / 128;  // 512
    const int M = E + N;

    const float* x     = (const float*)d_in[0];
    const int*   ei    = (const int*)d_in[1];
    const int*   batch = (const int*)d_in[2];
    const float* eps   = (const float*)d_in[3];
    const float* W1  = (const float*)d_in[4];  const float* b1  = (const float*)d_in[5];
    const float* W2  = (const float*)d_in[6];  const float* b2  = (const float*)d_in[7];
    const float* W3  = (const float*)d_in[8];  const float* b3  = (const float*)d_in[9];
    const float* Wmu = (const float*)d_in[10]; const float* bmu = (const float*)d_in[11];
    const float* Wlv = (const float*)d_in[12]; const float* blv = (const float*)d_in[13];
    const float* fc1w = (const float*)d_in[14]; const float* fc1b = (const float*)d_in[15];
    const float* fc2w = (const float*)d_in[16]; const float* fc2b = (const float*)d_in[17];

    const int* e_row = ei;
    const int* e_col = ei + E;

    float* out  = (float*)d_out;
    float* amvo = out;
    float* mu   = out + (size_t)N * F4;
    float* lv   = out + 2 * (size_t)N * F4;
    float* pmvo = out + 3 * (size_t)N * F4;

    // --- workspace carve ---
    char* w = (char*)d_ws;
    auto alloc = [&](size_t bytes) -> void* {
        void* p = (void*)w;
        w += (bytes + 255) & ~(size_t)255;
        return p;
    };
    float* dinv    = (float*)alloc((size_t)N * 4);
    int*   counts  = (int*)alloc((size_t)N * 4);
    int*   offsets = (int*)alloc((size_t)(N + 1) * 4);
    int*   csr_row = (int*)alloc((size_t)M * 4);
    float* csr_nrm = (float*)alloc((size_t)M * 4);
    int*   gstart  = (int*)alloc((size_t)(B + 1) * 4);
    unsigned short* xb  = (unsigned short*)alloc((size_t)N * F0 * 2);
    unsigned short* h1  = (unsigned short*)alloc((size_t)N * 128 * 2);
    unsigned short* h2  = (unsigned short*)alloc((size_t)N * 192 * 2);
    unsigned short* h3  = (unsigned short*)alloc((size_t)N * 256 * 2);
    unsigned short* wt1 = (unsigned short*)alloc((size_t)64 * 128 * 2);
    unsigned short* wt2 = (unsigned short*)alloc((size_t)128 * 192 * 2);
    unsigned short* wt3 = (unsigned short*)alloc((size_t)192 * 256 * 2);
    unsigned short* wtm = (unsigned short*)alloc((size_t)256 * 256 * 2);
    unsigned short* wtl = (unsigned short*)alloc((size_t)256 * 256 * 2);
    float* x2  = (float*)alloc((size_t)B * F4 * 4);
    float* hid = (float*)alloc((size_t)B * 1024 * 4);
    (void)ws_size; (void)n_in;

    // --- 1. graph structure ---
    hipMemsetAsync(counts, 0, (size_t)N * 4, stream);
    k_count<<<ceil_div(E, THREADS), THREADS, 0, stream>>>(e_col, counts, E);
    k_dinv<<<ceil_div(N, THREADS), THREADS, 0, stream>>>(counts, dinv, N);
    k_scan<<<1, 1024, 0, stream>>>(counts, offsets, N);
    k_init_cursor<<<ceil_div(N, THREADS), THREADS, 0, stream>>>(offsets, counts, N);
    k_scatter<<<ceil_div(E + N, THREADS), THREADS, 0, stream>>>(
        e_row, e_col, dinv, counts, csr_row, csr_nrm, E, N);

    // --- 2. casts + weight prep ---
    k_cast_bf16<<<ceil_div(N * F0, THREADS), THREADS, 0, stream>>>(x, xb, N * F0);
    k_prep_w<<<ceil_div(64 * 128, THREADS), THREADS, 0, stream>>>(W1, wt1, 64, 128);
    k_prep_w<<<ceil_div(128 * 192, THREADS), THREADS, 0, stream>>>(W2, wt2, 128, 192);
    k_prep_w<<<ceil_div(192 * 256, THREADS), THREADS, 0, stream>>>(W3, wt3, 192, 256);
    k_prep_w<<<ceil_div(256 * 256, THREADS), THREADS, 0, stream>>>(Wmu, wtm, 256, 256);
    k_prep_w<<<ceil_div(256 * 256, THREADS), THREADS, 0, stream>>>(Wlv, wtl, 256, 256);

    const int nbm = ceil_div(N, 128);          // 782

    // --- 3. GCN stack: fused agg+GEMM per layer ---
    k_fused_relu<64, 2><<<nbm, 512, 0, stream>>>(
        xb, offsets, csr_row, csr_nrm, wt1, b1, h1, N);
    k_fused_relu<128, 3><<<nbm, 512, 0, stream>>>(
        h1, offsets, csr_row, csr_nrm, wt2, b2, h2, N);
    k_fused_relu<192, 4><<<nbm, 512, 0, stream>>>(
        h2, offsets, csr_row, csr_nrm, wt3, b3, h3, N);
    k_fused_dual<<<nbm, 512, 0, stream>>>(
        h3, offsets, csr_row, csr_nrm, wtm, wtl, bmu, blv, eps,
        mu, lv, amvo, N);

    // --- 4. pool + MLP (fp32) ---
    k_gstart<<<ceil_div(B + 1, THREADS), THREADS, 0, stream>>>(batch, gstart, N, B);
    {
        dim3 gg(B, F4 / 64);
        dim3 blk(64, 4);
        k_pool_max<<<gg, blk, 0, stream>>>(h3, gstart, x2, F4);
    }
    k_fc1<<<B, 256, 0, stream>>>(x2, fc1w, fc1b, hid, F4, 1024);
    k_fc2<<<B, 128, 0, stream>>>(hid, fc2w, fc2b, pmvo, 1024, 128);
}

// Round 6
// 1073.037 us; speedup vs baseline: 1.3744x; 1.3744x over previous
//
#include <hip/hip_runtime.h>
#include <hip/hip_bf16.h>
#include <math.h>

// ---------------------------------------------------------------------------
// GCN-VAE encoder, round 8.
// r7 post-mortem: agg+GEMM fusion REGRESSED (531us dual, occ 18%): gather is
// latency-bound and lives on wave concurrency; 67.6KB LDS capped 2 blocks/CU
// and the fused gather re-walked the slot list CH times. Reverted to r6.
// r8 changes on top of r6:
//   - k_agg: slot loop unrolled x2 with independent accumulator pairs ->
//     2 random row-loads in flight per thread (gather is the ~40% block,
//     latency-bound at ~1.5-2TB/s on L3-resident rows).
//   - 5x k_prep_w -> 1x k_prep_all (launch overhead).
//   - k_gstart folded into k_pool_max (redundant binary search per thread).
// GEMMs unchanged from r6: barrier-free K-loop, full-B-in-LDS, XCD grouping.
// ---------------------------------------------------------------------------

#define THREADS 256

typedef short s8v __attribute__((ext_vector_type(8)));   // 8 bf16 = 4 VGPR
typedef float f4v __attribute__((ext_vector_type(4)));   // MFMA accum

__device__ inline float bf_lo(unsigned int u) {
    union { unsigned int i; float f; } c; c.i = u << 16; return c.f;
}
__device__ inline float bf_hi(unsigned int u) {
    union { unsigned int i; float f; } c; c.i = u & 0xffff0000u; return c.f;
}
__device__ inline unsigned short f2bf(float f) {
    __hip_bfloat16 h = __float2bfloat16(f);
    return *reinterpret_cast<unsigned short*>(&h);
}
__device__ inline float bf2f(unsigned short u) {
    union { unsigned int i; float f; } c; c.i = ((unsigned int)u) << 16; return c.f;
}

// ------------------------- graph structure ---------------------------------

__global__ void k_count(const int* __restrict__ col, int* __restrict__ counts, int E) {
    int e = blockIdx.x * blockDim.x + threadIdx.x;
    if (e < E) atomicAdd(&counts[col[e]], 1);
}

__global__ void k_dinv(const int* __restrict__ counts, float* __restrict__ dinv, int N) {
    int i = blockIdx.x * blockDim.x + threadIdx.x;
    if (i < N) dinv[i] = rsqrtf((float)(counts[i] + 1));   // +1 self loop
}

__global__ __launch_bounds__(1024) void k_scan(const int* __restrict__ counts,
                                               int* __restrict__ offsets, int N) {
    __shared__ int ssum[1024];
    int tid = threadIdx.x;
    int chunk = (N + 1023) / 1024;
    int begin = tid * chunk;
    int end = begin + chunk; if (end > N) end = N;
    int s = 0;
    for (int i = begin; i < end; ++i) s += counts[i] + 1;
    ssum[tid] = s;
    __syncthreads();
    for (int off = 1; off < 1024; off <<= 1) {
        int v = 0;
        if (tid >= off) v = ssum[tid - off];
        __syncthreads();
        if (tid >= off) ssum[tid] += v;
        __syncthreads();
    }
    int prefix = (tid == 0) ? 0 : ssum[tid - 1];
    for (int i = begin; i < end; ++i) {
        offsets[i] = prefix;
        prefix += counts[i] + 1;
    }
    if (end == N && begin < N) offsets[N] = prefix;
}

__global__ void k_init_cursor(const int* __restrict__ offsets, int* __restrict__ cursor, int N) {
    int i = blockIdx.x * blockDim.x + threadIdx.x;
    if (i < N) cursor[i] = offsets[i];
}

__global__ void k_scatter(const int* __restrict__ row, const int* __restrict__ col,
                          const float* __restrict__ dinv, int* __restrict__ cursor,
                          int* __restrict__ csr_row, float* __restrict__ csr_norm,
                          int E, int N) {
    int e = blockIdx.x * blockDim.x + threadIdx.x;
    if (e < E) {
        int r = row[e], c = col[e];
        int slot = atomicAdd(&cursor[c], 1);
        csr_row[slot] = r;
        csr_norm[slot] = dinv[r] * dinv[c];
    } else if (e < E + N) {
        int i = e - E;
        int slot = atomicAdd(&cursor[i], 1);
        csr_row[slot] = i;
        float d = dinv[i];
        csr_norm[slot] = d * d;
    }
}

// ------------------------- casts / weight prep -----------------------------

__global__ void k_cast_bf16(const float* __restrict__ src, unsigned short* __restrict__ dst, int n) {
    int i = blockIdx.x * blockDim.x + threadIdx.x;
    if (i < n) dst[i] = f2bf(src[i]);
}

// all five W [K,Nc] fp32 -> WT [Nc,K] bf16 in one launch
__global__ void k_prep_all(const float* __restrict__ W1, const float* __restrict__ W2,
                           const float* __restrict__ W3, const float* __restrict__ Wm,
                           const float* __restrict__ Wl,
                           unsigned short* __restrict__ o1, unsigned short* __restrict__ o2,
                           unsigned short* __restrict__ o3, unsigned short* __restrict__ om,
                           unsigned short* __restrict__ ol) {
    const int s1 = 64 * 128, s2 = s1 + 128 * 192, s3 = s2 + 192 * 256,
              s4 = s3 + 256 * 256, s5 = s4 + 256 * 256;
    int id = blockIdx.x * blockDim.x + threadIdx.x;
    if (id < s1)      { int t = id;      int k = t / 128, n = t % 128; o1[n *  64 + k] = f2bf(W1[t]); }
    else if (id < s2) { int t = id - s1; int k = t / 192, n = t % 192; o2[n * 128 + k] = f2bf(W2[t]); }
    else if (id < s3) { int t = id - s2; int k = t / 256, n = t % 256; o3[n * 192 + k] = f2bf(W3[t]); }
    else if (id < s4) { int t = id - s3; int k = t / 256, n = t % 256; om[n * 256 + k] = f2bf(Wm[t]); }
    else if (id < s5) { int t = id - s4; int k = t / 256, n = t % 256; ol[n * 256 + k] = f2bf(Wl[t]); }
}

// ------------------------- aggregation (gather, bf16 in/out) ---------------
// block: (F/8, nodes_per_block). Each thread owns 8 channels of one node.
// Slot loop unrolled x2 with independent accumulators: 2 random row-loads
// in flight per thread (latency-bound gather -> MLP doubles).
__global__ void k_agg(const unsigned short* __restrict__ h,
                      const int* __restrict__ offsets,
                      const int* __restrict__ csr_row,
                      const float* __restrict__ csr_nrm,
                      unsigned short* __restrict__ g, int N, int F) {
    int node = blockIdx.x * blockDim.y + threadIdx.y;
    if (node >= N) return;
    int c8 = threadIdx.x * 8;
    int off0 = offsets[node], off1 = offsets[node + 1];
    float a0=0.f,a1=0.f,a2=0.f,a3=0.f,a4=0.f,a5=0.f,a6=0.f,a7=0.f;
    float b0=0.f,b1=0.f,b2=0.f,b3=0.f,b4=0.f,b5=0.f,b6=0.f,b7=0.f;
    int sl = off0;
    for (; sl + 1 < off1; sl += 2) {
        int   r0 = csr_row[sl],     r1 = csr_row[sl + 1];
        float w0 = csr_nrm[sl],     w1 = csr_nrm[sl + 1];
        uint4 v0 = *(const uint4*)(h + (size_t)r0 * F + c8);
        uint4 v1 = *(const uint4*)(h + (size_t)r1 * F + c8);
        a0 += w0 * bf_lo(v0.x); a1 += w0 * bf_hi(v0.x);
        a2 += w0 * bf_lo(v0.y); a3 += w0 * bf_hi(v0.y);
        a4 += w0 * bf_lo(v0.z); a5 += w0 * bf_hi(v0.z);
        a6 += w0 * bf_lo(v0.w); a7 += w0 * bf_hi(v0.w);
        b0 += w1 * bf_lo(v1.x); b1 += w1 * bf_hi(v1.x);
        b2 += w1 * bf_lo(v1.y); b3 += w1 * bf_hi(v1.y);
        b4 += w1 * bf_lo(v1.z); b5 += w1 * bf_hi(v1.z);
        b6 += w1 * bf_lo(v1.w); b7 += w1 * bf_hi(v1.w);
    }
    if (sl < off1) {
        int   r0 = csr_row[sl];
        float w0 = csr_nrm[sl];
        uint4 v0 = *(const uint4*)(h + (size_t)r0 * F + c8);
        a0 += w0 * bf_lo(v0.x); a1 += w0 * bf_hi(v0.x);
        a2 += w0 * bf_lo(v0.y); a3 += w0 * bf_hi(v0.y);
        a4 += w0 * bf_lo(v0.z); a5 += w0 * bf_hi(v0.z);
        a6 += w0 * bf_lo(v0.w); a7 += w0 * bf_hi(v0.w);
    }
    a0 += b0; a1 += b1; a2 += b2; a3 += b3;
    a4 += b4; a5 += b5; a6 += b6; a7 += b7;
    uint4 o;
    o.x = (unsigned)f2bf(a0) | ((unsigned)f2bf(a1) << 16);
    o.y = (unsigned)f2bf(a2) | ((unsigned)f2bf(a3) << 16);
    o.z = (unsigned)f2bf(a4) | ((unsigned)f2bf(a5) << 16);
    o.w = (unsigned)f2bf(a6) | ((unsigned)f2bf(a7) << 16);
    *(uint4*)(g + (size_t)node * F + c8) = o;
}

// ------------------------- bf16 MFMA GEMM ----------------------------------
// C[M,Nc] = A[M,K](bf16) @ W (WT[Nc,K] bf16), +bias, opt relu.
// BM=128, BN=64, 512 threads = 8 waves x 16 rows. FULL B staged in LDS once
// (64 x K bf16 <= 34KB), then a barrier-free K-loop: A fragments stream
// global->reg. Block decode groups the NB bn-siblings of one bm on one XCD.
#define GBM 128
#define GBN 64
#define GBK 64
#define LDBMAX 264   // max (K+8) shorts: K<=256

__global__ __launch_bounds__(512) void k_gemm_mfma(
    const unsigned short* __restrict__ A,
    const unsigned short* __restrict__ WT,
    const float* __restrict__ bias,
    void* __restrict__ Cout, int M, int K, int Nc,
    int dorelu, int out_bf16) {
    __shared__ unsigned short sB[64 * LDBMAX];
    const int tid = threadIdx.x;
    const int wave = tid >> 6;          // 0..7, owns 16 rows
    const int lane = tid & 63;

    const int nbm = (M + GBM - 1) / GBM;
    const int NB = Nc >> 6;
    const int grpsz = 8 * NB;
    const int id = blockIdx.x;
    const int bmi = (id / grpsz) * 8 + (id % 8);
    const int bni = (id % grpsz) >> 3;
    if (bmi >= nbm) return;
    const int bm = bmi * GBM;
    const int bn = bni * GBN;

    const int ldb = K + 8;
    const int kc8 = K >> 3;
    for (int l = tid; l < 64 * kc8; l += 512) {
        int row = l / kc8, kc = (l - row * kc8) * 8;
        *(uint4*)(&sB[row * ldb + kc]) =
            *(const uint4*)(WT + (size_t)(bn + row) * K + kc);
    }
    __syncthreads();

    f4v acc[4];
    #pragma unroll
    for (int j = 0; j < 4; ++j) acc[j] = (f4v){0.f, 0.f, 0.f, 0.f};

    const int fr = lane & 15;
    const int fk = (lane >> 4) * 8;
    const int gm = bm + wave * 16 + fr;
    const unsigned short* Arow = A + (size_t)gm * K;
    const bool inM = (gm < M);

    for (int k0 = 0; k0 < K; k0 += GBK) {
        #pragma unroll
        for (int ks = 0; ks < 2; ++ks) {
            int kk = k0 + ks * 32 + fk;
            s8v a0 = inM ? *(const s8v*)(Arow + kk)
                         : (s8v){0, 0, 0, 0, 0, 0, 0, 0};
            #pragma unroll
            for (int nt = 0; nt < 4; ++nt) {
                s8v b = *(const s8v*)(&sB[(nt * 16 + fr) * ldb + kk]);
                acc[nt] = __builtin_amdgcn_mfma_f32_16x16x32_bf16(a0, b, acc[nt], 0, 0, 0);
            }
        }
    }

    const int col_l = lane & 15;
    const int row_q = (lane >> 4) * 4;
    #pragma unroll
    for (int nt = 0; nt < 4; ++nt) {
        #pragma unroll
        for (int i = 0; i < 4; ++i) {
            int row = bm + wave * 16 + row_q + i;
            int col = bn + nt * 16 + col_l;
            if (row < M) {
                float v = acc[nt][i] + bias[col];
                if (dorelu) v = fmaxf(v, 0.f);
                if (out_bf16)
                    ((unsigned short*)Cout)[(size_t)row * Nc + col] = f2bf(v);
                else
                    ((float*)Cout)[(size_t)row * Nc + col] = v;
            }
        }
    }
}

// ------------------------- dual bf16 MFMA GEMM + reparam epilogue ----------
__global__ __launch_bounds__(512) void k_gemm_mfma_dual(
    const unsigned short* __restrict__ A,
    const unsigned short* __restrict__ WTm,
    const unsigned short* __restrict__ WTl,
    const float* __restrict__ bmu,
    const float* __restrict__ blv,
    const float* __restrict__ eps,
    float* __restrict__ mu,
    float* __restrict__ lv,
    float* __restrict__ amvo,
    int M, int K, int Nc) {
    __shared__ unsigned short sBm[64 * LDBMAX];
    __shared__ unsigned short sBl[64 * LDBMAX];
    const int tid = threadIdx.x;
    const int wave = tid >> 6;
    const int lane = tid & 63;

    const int nbm = (M + GBM - 1) / GBM;
    const int NB = Nc >> 6;
    const int grpsz = 8 * NB;
    const int id = blockIdx.x;
    const int bmi = (id / grpsz) * 8 + (id % 8);
    const int bni = (id % grpsz) >> 3;
    if (bmi >= nbm) return;
    const int bm = bmi * GBM;
    const int bn = bni * GBN;

    const int ldb = K + 8;
    const int kc8 = K >> 3;
    for (int l = tid; l < 64 * kc8; l += 512) {
        int row = l / kc8, kc = (l - row * kc8) * 8;
        *(uint4*)(&sBm[row * ldb + kc]) =
            *(const uint4*)(WTm + (size_t)(bn + row) * K + kc);
        *(uint4*)(&sBl[row * ldb + kc]) =
            *(const uint4*)(WTl + (size_t)(bn + row) * K + kc);
    }
    __syncthreads();

    f4v accM[4], accL[4];
    #pragma unroll
    for (int j = 0; j < 4; ++j) {
        accM[j] = (f4v){0.f, 0.f, 0.f, 0.f};
        accL[j] = (f4v){0.f, 0.f, 0.f, 0.f};
    }

    const int fr = lane & 15;
    const int fk = (lane >> 4) * 8;
    const int gm = bm + wave * 16 + fr;
    const unsigned short* Arow = A + (size_t)gm * K;
    const bool inM = (gm < M);

    for (int k0 = 0; k0 < K; k0 += GBK) {
        #pragma unroll
        for (int ks = 0; ks < 2; ++ks) {
            int kk = k0 + ks * 32 + fk;
            s8v a0 = inM ? *(const s8v*)(Arow + kk)
                         : (s8v){0, 0, 0, 0, 0, 0, 0, 0};
            #pragma unroll
            for (int nt = 0; nt < 4; ++nt) {
                s8v bm_ = *(const s8v*)(&sBm[(nt * 16 + fr) * ldb + kk]);
                s8v bl_ = *(const s8v*)(&sBl[(nt * 16 + fr) * ldb + kk]);
                accM[nt] = __builtin_amdgcn_mfma_f32_16x16x32_bf16(a0, bm_, accM[nt], 0, 0, 0);
                accL[nt] = __builtin_amdgcn_mfma_f32_16x16x32_bf16(a0, bl_, accL[nt], 0, 0, 0);
            }
        }
    }

    const int col_l = lane & 15;
    const int row_q = (lane >> 4) * 4;
    #pragma unroll
    for (int nt = 0; nt < 4; ++nt) {
        int col = bn + nt * 16 + col_l;
        float bM = bmu[col];
        float bL = blv[col];
        #pragma unroll
        for (int i = 0; i < 4; ++i) {
            int row = bm + wave * 16 + row_q + i;
            if (row < M) {
                size_t idx = (size_t)row * Nc + col;
                float vm = accM[nt][i] + bM;
                float vl = accL[nt][i] + bL;
                mu[idx] = vm;
                lv[idx] = vl;
                amvo[idx] = vm + eps[idx] * expf(0.5f * vl);
            }
        }
    }
}

// ------------------------- FC layers (fp32, latency-optimized) -------------
__global__ __launch_bounds__(256) void k_fc1(const float* __restrict__ x2,
                                             const float* __restrict__ W,
                                             const float* __restrict__ bias,
                                             float* __restrict__ hid,
                                             int K, int Nc) {
    const int m = blockIdx.x;
    const int t = threadIdx.x;
    __shared__ float sx[256];
    for (int k = t; k < K; k += 256) sx[k] = x2[(size_t)m * K + k];
    __syncthreads();
    const int nc4 = Nc >> 2;
    const float4* Wv = (const float4*)W;
    float4 acc = make_float4(0.f, 0.f, 0.f, 0.f);
    #pragma unroll 4
    for (int k = 0; k < K; ++k) {
        float a = sx[k];
        float4 w = Wv[(size_t)k * nc4 + t];
        acc.x += a * w.x; acc.y += a * w.y;
        acc.z += a * w.z; acc.w += a * w.w;
    }
    float4 b = ((const float4*)bias)[t];
    float4 r;
    r.x = fmaxf(acc.x + b.x, 0.f);
    r.y = fmaxf(acc.y + b.y, 0.f);
    r.z = fmaxf(acc.z + b.z, 0.f);
    r.w = fmaxf(acc.w + b.w, 0.f);
    ((float4*)hid)[(size_t)m * nc4 + t] = r;
}

__global__ __launch_bounds__(128) void k_fc2(const float* __restrict__ hid,
                                             const float* __restrict__ W,
                                             const float* __restrict__ bias,
                                             float* __restrict__ out,
                                             int K, int Nc) {
    const int m = blockIdx.x;
    const int c = threadIdx.x;
    __shared__ float sh[1024];
    for (int k = c; k < K; k += 128) sh[k] = hid[(size_t)m * K + k];
    __syncthreads();
    float a0 = 0.f, a1 = 0.f, a2 = 0.f, a3 = 0.f;
    for (int k = 0; k < K; k += 4) {
        a0 += sh[k    ] * W[(size_t)(k    ) * Nc + c];
        a1 += sh[k + 1] * W[(size_t)(k + 1) * Nc + c];
        a2 += sh[k + 2] * W[(size_t)(k + 2) * Nc + c];
        a3 += sh[k + 3] * W[(size_t)(k + 3) * Nc + c];
    }
    out[(size_t)m * Nc + c] = (a0 + a1) + (a2 + a3) + bias[c];
}

// ------------------------- pool (gstart folded in) -------------------------
// max-pool over bf16 h3 -> fp32 x2. grid (B, F/64), block (64,4).
// Graph start/end found via redundant per-thread binary search on batch.
__global__ void k_pool_max(const unsigned short* __restrict__ h,
                           const int* __restrict__ batch,
                           float* __restrict__ x2, int F, int Nn) {
    int b = blockIdx.x;
    int c = blockIdx.y * 64 + threadIdx.x;
    int s, e;
    { int lo = 0, hi = Nn;
      while (lo < hi) { int mid = (lo + hi) >> 1; if (batch[mid] < b) lo = mid + 1; else hi = mid; }
      s = lo; }
    { int lo = s, hi = Nn;
      while (lo < hi) { int mid = (lo + hi) >> 1; if (batch[mid] < b + 1) lo = mid + 1; else hi = mid; }
      e = lo; }
    float mv = -INFINITY;
    for (int i = s + threadIdx.y; i < e; i += 4)
        mv = fmaxf(mv, bf2f(h[(size_t)i * F + c]));
    __shared__ float red[4][64];
    red[threadIdx.y][threadIdx.x] = mv;
    __syncthreads();
    if (threadIdx.y == 0) {
        mv = fmaxf(fmaxf(red[0][threadIdx.x], red[1][threadIdx.x]),
                   fmaxf(red[2][threadIdx.x], red[3][threadIdx.x]));
        x2[(size_t)b * F + c] = mv;
    }
}

static inline int ceil_div(int a, int b) { return (a + b - 1) / b; }

extern "C" void kernel_launch(void* const* d_in, const int* in_sizes, int n_in,
                              void* d_out, int out_size, void* d_ws, size_t ws_size,
                              hipStream_t stream) {
    const int F0 = 64;
    const int N = in_sizes[0] / F0;            // 100000
    const int E = in_sizes[1] / 2;             // 400000
    const int F4 = 4 * F0;                     // 256
    const int B = (out_size - 3 * N * F4) / 128;  // 512
    const int M = E + N;

    const float* x     = (const float*)d_in[0];
    const int*   ei    = (const int*)d_in[1];
    const int*   batch = (const int*)d_in[2];
    const float* eps   = (const float*)d_in[3];
    const float* W1  = (const float*)d_in[4];  const float* b1  = (const float*)d_in[5];
    const float* W2  = (const float*)d_in[6];  const float* b2  = (const float*)d_in[7];
    const float* W3  = (const float*)d_in[8];  const float* b3  = (const float*)d_in[9];
    const float* Wmu = (const float*)d_in[10]; const float* bmu = (const float*)d_in[11];
    const float* Wlv = (const float*)d_in[12]; const float* blv = (const float*)d_in[13];
    const float* fc1w = (const float*)d_in[14]; const float* fc1b = (const float*)d_in[15];
    const float* fc2w = (const float*)d_in[16]; const float* fc2b = (const float*)d_in[17];

    const int* e_row = ei;
    const int* e_col = ei + E;

    float* out  = (float*)d_out;
    float* amvo = out;
    float* mu   = out + (size_t)N * F4;
    float* lv   = out + 2 * (size_t)N * F4;
    float* pmvo = out + 3 * (size_t)N * F4;

    // --- workspace carve ---
    char* w = (char*)d_ws;
    auto alloc = [&](size_t bytes) -> void* {
        void* p = (void*)w;
        w += (bytes + 255) & ~(size_t)255;
        return p;
    };
    float* dinv    = (float*)alloc((size_t)N * 4);
    int*   counts  = (int*)alloc((size_t)N * 4);
    int*   offsets = (int*)alloc((size_t)(N + 1) * 4);
    int*   csr_row = (int*)alloc((size_t)M * 4);
    float* csr_nrm = (float*)alloc((size_t)M * 4);
    unsigned short* xb  = (unsigned short*)alloc((size_t)N * F0 * 2);
    unsigned short* h1  = (unsigned short*)alloc((size_t)N * 128 * 2);
    unsigned short* h2  = (unsigned short*)alloc((size_t)N * 192 * 2);
    unsigned short* h3  = (unsigned short*)alloc((size_t)N * 256 * 2);
    unsigned short* g   = (unsigned short*)alloc((size_t)N * 256 * 2);  // reused g1..g4
    unsigned short* wt1 = (unsigned short*)alloc((size_t)64 * 128 * 2);
    unsigned short* wt2 = (unsigned short*)alloc((size_t)128 * 192 * 2);
    unsigned short* wt3 = (unsigned short*)alloc((size_t)192 * 256 * 2);
    unsigned short* wtm = (unsigned short*)alloc((size_t)256 * 256 * 2);
    unsigned short* wtl = (unsigned short*)alloc((size_t)256 * 256 * 2);
    float* x2  = (float*)alloc((size_t)B * F4 * 4);
    float* hid = (float*)alloc((size_t)B * 1024 * 4);
    (void)ws_size; (void)n_in;

    // --- 1. graph structure ---
    hipMemsetAsync(counts, 0, (size_t)N * 4, stream);
    k_count<<<ceil_div(E, THREADS), THREADS, 0, stream>>>(e_col, counts, E);
    k_dinv<<<ceil_div(N, THREADS), THREADS, 0, stream>>>(counts, dinv, N);
    k_scan<<<1, 1024, 0, stream>>>(counts, offsets, N);
    k_init_cursor<<<ceil_div(N, THREADS), THREADS, 0, stream>>>(offsets, counts, N);
    k_scatter<<<ceil_div(E + N, THREADS), THREADS, 0, stream>>>(
        e_row, e_col, dinv, counts, csr_row, csr_nrm, E, N);

    // --- 2. casts + weight prep ---
    k_cast_bf16<<<ceil_div(N * F0, THREADS), THREADS, 0, stream>>>(x, xb, N * F0);
    {
        const int tot = 64 * 128 + 128 * 192 + 192 * 256 + 2 * 256 * 256;
        k_prep_all<<<ceil_div(tot, THREADS), THREADS, 0, stream>>>(
            W1, W2, W3, Wmu, Wlv, wt1, wt2, wt3, wtm, wtl);
    }

    const int nbm = ceil_div(N, GBM);          // 782
    const int nbm8 = ceil_div(nbm, 8) * 8;     // 784

    // --- 3. GCN stack: agg -> transform ---
    // g1 = agg(xb) [N,64]; h1 = relu(g1@W1+b1) [N,128]
    {
        dim3 blk(8, 32); // 64ch
        k_agg<<<ceil_div(N, 32), blk, 0, stream>>>(xb, offsets, csr_row, csr_nrm, g, N, 64);
        k_gemm_mfma<<<nbm8 * 2, 512, 0, stream>>>(g, wt1, b1, h1, N, 64, 128, 1, 1);
    }
    // g2 = agg(h1) [N,128]; h2 = relu(g2@W2+b2) [N,192]
    {
        dim3 blk(16, 16);
        k_agg<<<ceil_div(N, 16), blk, 0, stream>>>(h1, offsets, csr_row, csr_nrm, g, N, 128);
        k_gemm_mfma<<<nbm8 * 3, 512, 0, stream>>>(g, wt2, b2, h2, N, 128, 192, 1, 1);
    }
    // g3 = agg(h2) [N,192]; h3 = relu(g3@W3+b3) [N,256]
    {
        dim3 blk(24, 8);
        k_agg<<<ceil_div(N, 8), blk, 0, stream>>>(h2, offsets, csr_row, csr_nrm, g, N, 192);
        k_gemm_mfma<<<nbm8 * 4, 512, 0, stream>>>(g, wt3, b3, h3, N, 192, 256, 1, 1);
    }
    // g4 = agg(h3) [N,256]; fused: mu, lv, amvo in one pass
    {
        dim3 blk(32, 8);
        k_agg<<<ceil_div(N, 8), blk, 0, stream>>>(h3, offsets, csr_row, csr_nrm, g, N, 256);
        k_gemm_mfma_dual<<<nbm8 * 4, 512, 0, stream>>>(g, wtm, wtl, bmu, blv, eps,
                                                       mu, lv, amvo, N, 256, 256);
    }

    // --- 4. pool + MLP (fp32) ---
    {
        dim3 gg(B, F4 / 64);
        dim3 blk(64, 4);
        k_pool_max<<<gg, blk, 0, stream>>>(h3, batch, x2, F4, N);
    }
    k_fc1<<<B, 256, 0, stream>>>(x2, fc1w, fc1b, hid, F4, 1024);
    k_fc2<<<B, 128, 0, stream>>>(hid, fc2w, fc2b, pmvo, 1024, 128);
}